// Round 3
// baseline (300.507 us; speedup 1.0000x reference)
//
#include <hip/hip_runtime.h>

#define N_NODES 50000
#define N_EDGES 800000

typedef float f32x4 __attribute__((ext_vector_type(4)));
typedef short bf16x8 __attribute__((ext_vector_type(8)));

__device__ __forceinline__ float fast_tanh(float x) {
  // exact algebra: tanh(x) = 1 - 2/(exp(2x)+1)
  float e = __expf(2.0f * x);
  return 1.0f - 2.0f / (e + 1.0f);
}

__device__ __forceinline__ unsigned short f2bf_rne(float x) {
  unsigned u = __float_as_uint(x);
  unsigned r = u + 0x7FFFu + ((u >> 16) & 1u);
  return (unsigned short)(r >> 16);
}

// ---------- prep1: W12 = pi_W1 @ pi_W2  [128x64]; b12 = pi_b1 @ pi_W2 + pi_b2 [64]
__global__ __launch_bounds__(256) void prep1_kernel(
    const float* __restrict__ piW1, const float* __restrict__ pib1,
    const float* __restrict__ piW2, const float* __restrict__ pib2,
    float* __restrict__ W12, float* __restrict__ b12) {
  int gid = blockIdx.x * 256 + threadIdx.x;
  if (gid < 128 * 64) {
    int m = gid >> 6, c = gid & 63;
    float acc = 0.f;
    #pragma unroll 8
    for (int k = 0; k < 64; ++k) acc = fmaf(piW1[m * 64 + k], piW2[k * 64 + c], acc);
    W12[gid] = acc;
  } else if (gid < 128 * 64 + 64) {
    int c = gid - 128 * 64;
    float acc = pib2[c];
    for (int k = 0; k < 64; ++k) acc = fmaf(pib1[k], piW2[k * 64 + c], acc);
    b12[c] = acc;
  }
}

// ---------- prep_b: Bpack[ks][ct][lane][j] = bf16( W3i[kidx][col] )
// W3i[kidx][c] = sum_m piW3[k][m*8+b]*iiW1[m][c], kidx=k*8+b
// kidx = ks*32 + (lane>>4)*8 + j ; col = ct*16 + (lane&15)
__global__ __launch_bounds__(256) void prep_b_kernel(
    const float* __restrict__ piW3, const float* __restrict__ iiW1,
    unsigned short* __restrict__ Bpack) {
  int gid = blockIdx.x * 256 + threadIdx.x;  // 32768 total
  int j = gid & 7;
  int lane = (gid >> 3) & 63;
  int ct = (gid >> 9) & 3;
  int ks = gid >> 11;
  int kidx = ks * 32 + ((lane >> 4) << 3) + j;
  int col = ct * 16 + (lane & 15);
  int k = kidx >> 3, b = kidx & 7;
  float acc = 0.f;
  #pragma unroll 8
  for (int mm = 0; mm < 64; ++mm)
    acc = fmaf(piW3[k * 512 + mm * 8 + b], iiW1[mm * 64 + col], acc);
  Bpack[gid] = f2bf_rne(acc);
}

// ---------- prep_w2: W2pack[ks][ct][lane][j] = bf16( iiW2[kidx][col] )
__global__ __launch_bounds__(256) void prep_w2_kernel(
    const float* __restrict__ iiW2, unsigned short* __restrict__ W2pack) {
  int gid = blockIdx.x * 256 + threadIdx.x;  // 4096 total
  int j = gid & 7;
  int lane = (gid >> 3) & 63;
  int ct = (gid >> 9) & 3;
  int ks = gid >> 11;
  int kidx = ks * 32 + ((lane >> 4) << 3) + j;
  int col = ct * 16 + (lane & 15);
  W2pack[gid] = f2bf_rne(iiW2[kidx * 64 + col]);
}

// ---------- node: p1 = tanh(p@ppW1+b1)@ppW2+b2 ; qa = p1@W12[0:64]; qb = p1@W12[64:128]
__global__ __launch_bounds__(256) void node_kernel(
    const float* __restrict__ p,
    const float* __restrict__ ppW1, const float* __restrict__ ppb1,
    const float* __restrict__ ppW2, const float* __restrict__ ppb2,
    const float* __restrict__ W12,
    float* __restrict__ qa, float* __restrict__ qb) {
  __shared__ float sW1[64 * 64];
  __shared__ float sW2[64 * 64];
  __shared__ float sW12[128 * 64];
  __shared__ float sb1[64], sb2[64];
  __shared__ float sX[4][8][64];
  int tid = threadIdx.x;
  for (int i = tid; i < 64 * 64; i += 256) { sW1[i] = ppW1[i]; sW2[i] = ppW2[i]; }
  for (int i = tid; i < 128 * 64; i += 256) sW12[i] = W12[i];
  if (tid < 64) { sb1[tid] = ppb1[tid]; sb2[tid] = ppb2[tid]; }
  __syncthreads();
  int wave = tid >> 6, lane = tid & 63;
  int rowbase = blockIdx.x * 32 + wave * 8;

  float4* sXf4 = (float4*)&sX[wave][0][0];
  for (int t = lane; t < 128; t += 64) {
    int r = t >> 4, c4 = t & 15;
    int row = rowbase + r;
    float4 v = make_float4(0.f, 0.f, 0.f, 0.f);
    if (row < N_NODES) v = ((const float4*)p)[row * 16 + c4];
    sXf4[t] = v;
  }
  __syncthreads();

  float h[8];
  #pragma unroll
  for (int r = 0; r < 8; ++r) h[r] = sb1[lane];
  for (int k = 0; k < 64; ++k) {
    float w = sW1[k * 64 + lane];
    #pragma unroll
    for (int r = 0; r < 8; ++r) h[r] = fmaf(sX[wave][r][k], w, h[r]);
  }
  #pragma unroll
  for (int r = 0; r < 8; ++r) h[r] = fast_tanh(h[r]);
  __syncthreads();
  #pragma unroll
  for (int r = 0; r < 8; ++r) sX[wave][r][lane] = h[r];
  __syncthreads();

  float g[8];
  #pragma unroll
  for (int r = 0; r < 8; ++r) g[r] = sb2[lane];
  for (int k = 0; k < 64; ++k) {
    float w = sW2[k * 64 + lane];
    #pragma unroll
    for (int r = 0; r < 8; ++r) g[r] = fmaf(sX[wave][r][k], w, g[r]);
  }
  __syncthreads();
  #pragma unroll
  for (int r = 0; r < 8; ++r) sX[wave][r][lane] = g[r];
  __syncthreads();

  float a[8], b[8];
  #pragma unroll
  for (int r = 0; r < 8; ++r) { a[r] = 0.f; b[r] = 0.f; }
  for (int k = 0; k < 64; ++k) {
    float wa = sW12[k * 64 + lane];
    float wb = sW12[(64 + k) * 64 + lane];
    #pragma unroll
    for (int r = 0; r < 8; ++r) {
      float x = sX[wave][r][k];
      a[r] = fmaf(x, wa, a[r]);
      b[r] = fmaf(x, wb, b[r]);
    }
  }
  #pragma unroll
  for (int r = 0; r < 8; ++r) {
    int row = rowbase + r;
    if (row < N_NODES) {
      qa[row * 64 + lane] = a[r];
      qb[row * 64 + lane] = b[r];
    }
  }
}

// ---------- edge: h2 = qa[i]+qb[j]+b12 ; s = (h2 (x) basis) @ W3i + ii_b1 (MFMA, rne-bf16 A)
//                  t = tanh(s) ; i2 = t @ ii_W2 + ii_b2 (MFMA) ; out[idx_j] += i2 (atomic)
// 1024 threads = 16 waves, 256 edges/block. LDS union 64KB:
//   phase0 = h2 tile [256][64] f32, XOR-swizzled col (dw ^= (e&7)<<3)
//   phase1 = Bpack [16][4][64][8] bf16 (64KB)
//   phase2 = t tile [256][72] bf16 (36.9KB)
__global__ __launch_bounds__(1024, 8) void edge_kernel(
    const int* __restrict__ idx_i, const int* __restrict__ idx_j,
    const float* __restrict__ basis,
    const float* __restrict__ qa, const float* __restrict__ qb,
    const float* __restrict__ b12,
    const unsigned short* __restrict__ Bpack,
    const unsigned short* __restrict__ W2pack,
    const float* __restrict__ iib1, const float* __restrict__ iib2,
    float* __restrict__ out) {
  __shared__ __align__(16) unsigned short sB[32768];  // 64 KB
  float* sH2 = (float*)sB;
  unsigned short* sT = sB;

  int tid = threadIdx.x;
  int e0 = blockIdx.x * 256;

  // ---- phase 0: gather h2 into LDS (f32, swizzled)
  for (int t = tid; t < 4096; t += 1024) {
    int e = t >> 4, q = t & 15;
    int ii = idx_i[e0 + e];
    int jj = idx_j[e0 + e];
    float4 va = ((const float4*)qa)[ii * 16 + q];
    float4 vb = ((const float4*)qb)[jj * 16 + q];
    float4 vc = ((const float4*)b12)[q];
    float4 h;
    h.x = va.x + vb.x + vc.x;
    h.y = va.y + vb.y + vc.y;
    h.z = va.z + vb.z + vc.z;
    h.w = va.w + vb.w + vc.w;
    int dw = e * 64 + ((q * 4) ^ ((e & 7) << 3));  // XOR keeps 16B alignment
    *((float4*)(sH2 + dw)) = h;
  }
  __syncthreads();

  int w = tid >> 6, l = tid & 63;
  int m = l & 15, s = l >> 4;
  int eloc = w * 16 + m;        // this lane's edge row (A-operand row = l&15)
  int swz = (eloc & 7) << 3;

  // per-lane A inputs: h2[e][k] for k = 4*ks + s, and basis[e][0..8)
  float h2r[16];
  #pragma unroll
  for (int t = 0; t < 16; ++t) h2r[t] = sH2[eloc * 64 + ((t * 4 + s) ^ swz)];

  float bas[8];
  {
    const float4* bp = (const float4*)(basis + (size_t)(e0 + eloc) * 8);
    float4 b0 = bp[0], b1 = bp[1];
    bas[0] = b0.x; bas[1] = b0.y; bas[2] = b0.z; bas[3] = b0.w;
    bas[4] = b1.x; bas[5] = b1.y; bas[6] = b1.z; bas[7] = b1.w;
  }
  __syncthreads();

  // ---- phase 1: stage Bpack (64 KB) into LDS
  {
    const uint4* g = (const uint4*)Bpack;
    uint4* d = (uint4*)sB;
    #pragma unroll
    for (int t = 0; t < 4; ++t) d[tid + t * 1024] = g[tid + t * 1024];
  }
  __syncthreads();

  // C init with ii_b1 (col = ct*16 + m, same for the 4 rows)
  f32x4 c0, c1, c2, c3;
  {
    float v0 = iib1[m], v1 = iib1[16 + m], v2 = iib1[32 + m], v3 = iib1[48 + m];
    c0 = (f32x4){v0, v0, v0, v0};
    c1 = (f32x4){v1, v1, v1, v1};
    c2 = (f32x4){v2, v2, v2, v2};
    c3 = (f32x4){v3, v3, v3, v3};
  }

  // ---- main K-loop: 16 K-steps x 4 col-tiles, single rne-bf16 A = 64 MFMA/wave
  const bf16x8* Bl = (const bf16x8*)sB;
  #pragma unroll
  for (int ks = 0; ks < 16; ++ks) {
    bf16x8 B0 = Bl[(ks * 4 + 0) * 64 + l];
    bf16x8 B1 = Bl[(ks * 4 + 1) * 64 + l];
    bf16x8 B2 = Bl[(ks * 4 + 2) * 64 + l];
    bf16x8 B3 = Bl[(ks * 4 + 3) * 64 + l];
    float hv = h2r[ks];
    union { unsigned u[4]; bf16x8 v; } A;
    #pragma unroll
    for (int j = 0; j < 4; ++j) {
      float p0 = hv * bas[2 * j];
      float p1 = hv * bas[2 * j + 1];
      asm("v_cvt_pk_bf16_f32 %0, %1, %2" : "=v"(A.u[j]) : "v"(p0), "v"(p1));
    }
    c0 = __builtin_amdgcn_mfma_f32_16x16x32_bf16(A.v, B0, c0, 0, 0, 0);
    c1 = __builtin_amdgcn_mfma_f32_16x16x32_bf16(A.v, B1, c1, 0, 0, 0);
    c2 = __builtin_amdgcn_mfma_f32_16x16x32_bf16(A.v, B2, c2, 0, 0, 0);
    c3 = __builtin_amdgcn_mfma_f32_16x16x32_bf16(A.v, B3, c3, 0, 0, 0);
  }
  __syncthreads();  // all waves done reading Bpack region

  // ---- phase 2: tanh -> t tile (bf16)
  // C/D layout: col = ct*16 + m, row(local) = s*4 + r
  #pragma unroll
  for (int r = 0; r < 4; ++r) {
    int row = w * 16 + s * 4 + r;
    sT[row * 72 + 0 * 16 + m] = f2bf_rne(fast_tanh(c0[r]));
    sT[row * 72 + 1 * 16 + m] = f2bf_rne(fast_tanh(c1[r]));
    sT[row * 72 + 2 * 16 + m] = f2bf_rne(fast_tanh(c2[r]));
    sT[row * 72 + 3 * 16 + m] = f2bf_rne(fast_tanh(c3[r]));
  }
  __syncthreads();

  // ---- second GEMM: i2 = t @ ii_W2 + ii_b2   (K=64: 2 K-steps x 4 col-tiles)
  f32x4 d0, d1, d2, d3;
  {
    float v0 = iib2[m], v1 = iib2[16 + m], v2 = iib2[32 + m], v3 = iib2[48 + m];
    d0 = (f32x4){v0, v0, v0, v0};
    d1 = (f32x4){v1, v1, v1, v1};
    d2 = (f32x4){v2, v2, v2, v2};
    d3 = (f32x4){v3, v3, v3, v3};
  }
  const bf16x8* Wl = (const bf16x8*)W2pack;
  #pragma unroll
  for (int ks = 0; ks < 2; ++ks) {
    bf16x8 Af = *(const bf16x8*)(sT + eloc * 72 + ks * 32 + s * 8);
    d0 = __builtin_amdgcn_mfma_f32_16x16x32_bf16(Af, Wl[(ks * 4 + 0) * 64 + l], d0, 0, 0, 0);
    d1 = __builtin_amdgcn_mfma_f32_16x16x32_bf16(Af, Wl[(ks * 4 + 1) * 64 + l], d1, 0, 0, 0);
    d2 = __builtin_amdgcn_mfma_f32_16x16x32_bf16(Af, Wl[(ks * 4 + 2) * 64 + l], d2, 0, 0, 0);
    d3 = __builtin_amdgcn_mfma_f32_16x16x32_bf16(Af, Wl[(ks * 4 + 3) * 64 + l], d3, 0, 0, 0);
  }

  // ---- scatter-add by idx_j
  #pragma unroll
  for (int r = 0; r < 4; ++r) {
    int jj = idx_j[e0 + w * 16 + s * 4 + r];
    float* po = out + (size_t)jj * 64;
    atomicAdd(po + m, d0[r]);
    atomicAdd(po + 16 + m, d1[r]);
    atomicAdd(po + 32 + m, d2[r]);
    atomicAdd(po + 48 + m, d3[r]);
  }
}

extern "C" void kernel_launch(void* const* d_in, const int* in_sizes, int n_in,
                              void* d_out, int out_size, void* d_ws, size_t ws_size,
                              hipStream_t stream) {
  const float* p     = (const float*)d_in[0];
  const int*   idx_i = (const int*)d_in[1];
  const int*   idx_j = (const int*)d_in[2];
  const float* basis = (const float*)d_in[3];
  const float* ppW1  = (const float*)d_in[4];
  const float* ppb1  = (const float*)d_in[5];
  const float* ppW2  = (const float*)d_in[6];
  const float* ppb2  = (const float*)d_in[7];
  const float* piW1  = (const float*)d_in[8];
  const float* pib1  = (const float*)d_in[9];
  const float* piW2  = (const float*)d_in[10];
  const float* pib2  = (const float*)d_in[11];
  const float* piW3  = (const float*)d_in[12];
  const float* iiW1  = (const float*)d_in[13];
  const float* iib1  = (const float*)d_in[14];
  const float* iiW2  = (const float*)d_in[15];
  const float* iib2  = (const float*)d_in[16];

  float* ws  = (float*)d_ws;
  float* qa  = ws;                         // 3,200,000 floats
  float* qb  = ws + 3200000;               // 3,200,000 floats
  float* W12 = ws + 6400000;               // 8192
  float* b12 = ws + 6408192;               // 64
  unsigned short* Bpack  = (unsigned short*)(ws + 6408256);          // 32768 bf16 (64 KB)
  unsigned short* W2pack = (unsigned short*)(ws + 6408256 + 16384);  // 4096 bf16 (8 KB)

  hipMemsetAsync(d_out, 0, (size_t)out_size * sizeof(float), stream);
  prep1_kernel<<<33, 256, 0, stream>>>(piW1, pib1, piW2, pib2, W12, b12);
  prep_b_kernel<<<128, 256, 0, stream>>>(piW3, iiW1, Bpack);
  prep_w2_kernel<<<16, 256, 0, stream>>>(iiW2, W2pack);
  node_kernel<<<1563, 256, 0, stream>>>(p, ppW1, ppb1, ppW2, ppb2, W12, qa, qb);
  edge_kernel<<<3125, 1024, 0, stream>>>(idx_i, idx_j, basis, qa, qb, b12,
                                         Bpack, W2pack, iib1, iib2, (float*)d_out);
}